// Round 5
// baseline (631.468 us; speedup 1.0000x reference)
//
#include <hip/hip_runtime.h>
#include <math.h>

namespace {
constexpr int L1 = 13;   // 12 history layers + current
constexpr int LH = 12;
constexpr int B  = 4;
constexpr int S  = 1024;
constexpr int D  = 1024;
constexpr int NCH = 128;        // s-chunks per batch
constexpr int CH  = S / NCH;    // 8 s-rows per block
constexpr int NBLK = B * NCH;   // 512 blocks = 2/CU co-resident
constexpr float EPS = 1e-5f;

// ws float offsets
constexpr int OFF_FLAG = 0;           // NBLK ints (zeroed by memset each call)
constexpr int OFF_ZAGG = NBLK;        // NBLK floats: per-chunk z aggregate
constexpr int OFF_CS   = 2 * NBLK;    // NBLK*D floats: per-chunk U aggregate
}

// One kernel, decoupled-lookback scan over s-chunks.
// Block (b,ch) owns 8 consecutive s-rows, full D (256 thr x float4).
// Phase 1: per s-row: load 13 layer rows, block-reduce {sum,sumsq,wg-dot} per layer,
//   p = exp(score) (softmax shift-invariant, |score| <~ 5), keep inclusive local
//   cumsum of U in registers (Uc[8] float4/thread) and z in zc[8].
// Publish: chunk aggregates (U->ws CS, z->ws ZAGG), threadfence, release-store flag.
// Lookback: spin-acquire all same-b predecessor flags (all 512 blocks co-resident:
//   2 blocks/CU via __launch_bounds__(256,2) => no deadlock), sum their aggregates
//   (L2-resident), then h = (pre + Uc[j]) / (zpre + zc[j]) written straight to out.
__global__ __launch_bounds__(256, 2) void arm_fused(
    const float* __restrict__ hist, const float* __restrict__ cur,
    const float* __restrict__ w, const float* __restrict__ gamma,
    const float* __restrict__ beta, float* __restrict__ out,
    float* __restrict__ ws) {
    const int bid = blockIdx.x;
    const int b = bid >> 7, ch = bid & (NCH - 1);
    const int tid = threadIdx.x, lane = tid & 63, wid = tid >> 6;
    const int d = tid * 4;

    float4 wv = *(const float4*)(w + d);
    float4 gv = *(const float4*)(gamma + d);
    float4 bv = *(const float4*)(beta + d);
    float4 wg = {wv.x * gv.x, wv.y * gv.y, wv.z * gv.z, wv.w * gv.w};

    __shared__ float red[3 * L1][4];
    __shared__ float red2[2][4];

    {   // block totals sum(w*gamma), sum(w*beta)
        float a = wg.x + wg.y + wg.z + wg.w;
        float c = wv.x * bv.x + wv.y * bv.y + wv.z * bv.z + wv.w * bv.w;
#pragma unroll
        for (int o = 32; o > 0; o >>= 1) { a += __shfl_down(a, o); c += __shfl_down(c, o); }
        if (lane == 0) { red2[0][wid] = a; red2[1][wid] = c; }
    }
    __syncthreads();
    const float swg = red2[0][0] + red2[0][1] + red2[0][2] + red2[0][3];
    const float swb = red2[1][0] + red2[1][1] + red2[1][2] + red2[1][3];

    const size_t base = ((size_t)b * S + ch * CH) * D + d;
    float4 Uc[CH];
    float  zc[CH];
    float4 Usum = {0.f, 0.f, 0.f, 0.f};
    float  zsum = 0.f;

#pragma unroll
    for (int j = 0; j < CH; j++) {
        const size_t off = base + (size_t)j * D;
        float4 v[L1];
#pragma unroll
        for (int l = 0; l < LH; l++)
            v[l] = *(const float4*)(hist + (size_t)l * (B * S * D) + off);
        v[12] = *(const float4*)(cur + off);

#pragma unroll
        for (int l = 0; l < L1; l++) {
            float s1 = v[l].x + v[l].y + v[l].z + v[l].w;
            float s2 = v[l].x * v[l].x + v[l].y * v[l].y + v[l].z * v[l].z + v[l].w * v[l].w;
            float sw = wg.x * v[l].x + wg.y * v[l].y + wg.z * v[l].z + wg.w * v[l].w;
#pragma unroll
            for (int o = 32; o > 0; o >>= 1) {
                s1 += __shfl_down(s1, o);
                s2 += __shfl_down(s2, o);
                sw += __shfl_down(sw, o);
            }
            if (lane == 0) { red[3 * l][wid] = s1; red[3 * l + 1][wid] = s2; red[3 * l + 2][wid] = sw; }
        }
        __syncthreads();
        float4 acc = {0.f, 0.f, 0.f, 0.f};
        float zz = 0.f;
#pragma unroll
        for (int l = 0; l < L1; l++) {
            float s1 = red[3 * l][0] + red[3 * l][1] + red[3 * l][2] + red[3 * l][3];
            float s2 = red[3 * l + 1][0] + red[3 * l + 1][1] + red[3 * l + 1][2] + red[3 * l + 1][3];
            float sw = red[3 * l + 2][0] + red[3 * l + 2][1] + red[3 * l + 2][2] + red[3 * l + 2][3];
            float mu   = s1 * (1.0f / D);
            float var  = s2 * (1.0f / D) - mu * mu;
            float rstd = rsqrtf(var + EPS);
            float p = __expf(rstd * (sw - mu * swg) + swb);
            acc.x += p * v[l].x; acc.y += p * v[l].y; acc.z += p * v[l].z; acc.w += p * v[l].w;
            zz += p;
        }
        __syncthreads();   // red[] reused next iteration
        Usum.x += acc.x; Usum.y += acc.y; Usum.z += acc.z; Usum.w += acc.w;
        zsum += zz;
        Uc[j] = Usum; zc[j] = zsum;
    }

    // ---- publish chunk aggregate ----
    *(float4*)(ws + OFF_CS + (size_t)bid * D + d) = Usum;
    if (tid == 0) ws[OFF_ZAGG + bid] = zsum;
    __threadfence();      // make this thread's CS/z writes device-visible
    __syncthreads();      // all threads' fences complete before the flag
    int* flags = (int*)ws + OFF_FLAG;
    if (tid == 0)
        __hip_atomic_store(&flags[bid], 1, __ATOMIC_RELEASE, __HIP_MEMORY_SCOPE_AGENT);

    // ---- lookback: wait for all same-b predecessors ----
    const int cbase = b * NCH;
    if (tid < ch) {
        while (__hip_atomic_load(&flags[cbase + tid], __ATOMIC_ACQUIRE,
                                 __HIP_MEMORY_SCOPE_AGENT) == 0)
            __builtin_amdgcn_s_sleep(8);
    }
    __syncthreads();

    float4 pre = {0.f, 0.f, 0.f, 0.f};
    float zpre = 0.f;
    for (int c2 = 0; c2 < ch; c2++) {
        float4 t = *(const float4*)(ws + OFF_CS + (size_t)(cbase + c2) * D + d);
        pre.x += t.x; pre.y += t.y; pre.z += t.z; pre.w += t.w;
        zpre += ws[OFF_ZAGG + cbase + c2];
    }

    // ---- final: h = (pre + Uc) / (zpre + zc) ----
#pragma unroll
    for (int j = 0; j < CH; j++) {
        float rz = 1.0f / (zpre + zc[j]);
        float4 hv = {(pre.x + Uc[j].x) * rz, (pre.y + Uc[j].y) * rz,
                     (pre.z + Uc[j].z) * rz, (pre.w + Uc[j].w) * rz};
        *(float4*)(out + base + (size_t)j * D) = hv;
    }
}

extern "C" void kernel_launch(void* const* d_in, const int* in_sizes, int n_in,
                              void* d_out, int out_size, void* d_ws, size_t ws_size,
                              hipStream_t stream) {
    const float* hist  = (const float*)d_in[0];  // [12,B,S,D]
    const float* cur   = (const float*)d_in[1];  // [B,S,D]
    const float* w     = (const float*)d_in[2];  // [D]
    const float* gamma = (const float*)d_in[3];  // [D]
    const float* beta  = (const float*)d_in[4];  // [D]
    float* out = (float*)d_out;                  // [B,S,D]
    float* ws  = (float*)d_ws;

    // zero the lookback flags (2 KB) -- graph-capturable, re-runs every replay
    hipMemsetAsync(ws, 0, NBLK * sizeof(int), stream);
    arm_fused<<<NBLK, 256, 0, stream>>>(hist, cur, w, gamma, beta, out, ws);
}

// Round 6
// 62.307 us; speedup vs baseline: 10.1348x; 10.1348x over previous
//
#include <hip/hip_runtime.h>
#include <math.h>

namespace {
constexpr int L1 = 13;   // 12 history layers + current
constexpr int LH = 12;
constexpr int B  = 4;
constexpr int S  = 1024;
constexpr int D  = 1024;
constexpr int NCH  = 32;        // s-chunks for the scan tails
constexpr int CH   = S / NCH;   // 32
constexpr int DBLK = D / 256;   // 4

// float offsets into workspace (~570 KB used)
constexpr int OFF_Z    = 0;                    // [B*S] per-row softmax denom
constexpr int OFF_ZCUM = B * S;                // [B*S] inclusive prefix over s
constexpr int OFF_CS   = 2 * B * S;            // [B][NCH][D] chunk partial sums
constexpr float EPS = 1e-5f;
}

// K1: one WAVE per (b,s) row -- no LDS, no barriers, free-running waves.
// Lane holds 16 row elems (4x float4 at d = lane*4 + j*256). Per layer:
// butterfly-reduce {sum, sumsq, wg-dot} across 64 lanes (shfl_xor, all lanes
// get the total), score = rstd*(sw - mu*swg) + swb, p = exp(score)
// (softmax is shift-invariant; |score| <~ 5 so no max subtraction needed),
// acc += p*v, z += p.  U -> d_out, z -> ws.
__global__ __launch_bounds__(256) void arm_k1(const float* __restrict__ hist,
                                              const float* __restrict__ cur,
                                              const float* __restrict__ w,
                                              const float* __restrict__ gamma,
                                              const float* __restrict__ beta,
                                              float* __restrict__ U,
                                              float* __restrict__ ws) {
    const int tid = threadIdx.x, lane = tid & 63;
    const int gw = blockIdx.x * 4 + (tid >> 6);   // row id = b*S + s, [0, B*S)
    const int d0 = lane * 4;
    const size_t rowoff = (size_t)gw * D;

    // per-wave wg = w*gamma (kept in regs) + swg/swb scalars (butterfly)
    float4 wg[4];
    float swg_p = 0.f, swb_p = 0.f;
#pragma unroll
    for (int j = 0; j < 4; j++) {
        int d = d0 + j * 256;
        float4 wv = *(const float4*)(w + d);
        float4 gv = *(const float4*)(gamma + d);
        float4 bv = *(const float4*)(beta + d);
        wg[j] = {wv.x * gv.x, wv.y * gv.y, wv.z * gv.z, wv.w * gv.w};
        swg_p += wg[j].x + wg[j].y + wg[j].z + wg[j].w;
        swb_p += wv.x * bv.x + wv.y * bv.y + wv.z * bv.z + wv.w * bv.w;
    }
#pragma unroll
    for (int o = 32; o > 0; o >>= 1) {
        swg_p += __shfl_xor(swg_p, o);
        swb_p += __shfl_xor(swb_p, o);
    }
    const float swg = swg_p, swb = swb_p;

    float4 acc[4] = {{0,0,0,0},{0,0,0,0},{0,0,0,0},{0,0,0,0}};
    float z = 0.f;

#pragma unroll 2
    for (int l = 0; l < L1; l++) {
        const float* row = (l < LH ? hist + (size_t)l * (B * S * D) : cur) + rowoff;
        float4 v[4];
#pragma unroll
        for (int j = 0; j < 4; j++) v[j] = *(const float4*)(row + d0 + j * 256);

        float s1 = 0.f, s2 = 0.f, sw = 0.f;
#pragma unroll
        for (int j = 0; j < 4; j++) {
            s1 += v[j].x + v[j].y + v[j].z + v[j].w;
            s2 += v[j].x * v[j].x + v[j].y * v[j].y + v[j].z * v[j].z + v[j].w * v[j].w;
            sw += wg[j].x * v[j].x + wg[j].y * v[j].y + wg[j].z * v[j].z + wg[j].w * v[j].w;
        }
#pragma unroll
        for (int o = 32; o > 0; o >>= 1) {
            s1 += __shfl_xor(s1, o);
            s2 += __shfl_xor(s2, o);
            sw += __shfl_xor(sw, o);
        }
        float mu   = s1 * (1.0f / D);
        float var  = s2 * (1.0f / D) - mu * mu;
        float rstd = rsqrtf(var + EPS);
        float p = __expf(rstd * (sw - mu * swg) + swb);
#pragma unroll
        for (int j = 0; j < 4; j++) {
            acc[j].x += p * v[j].x; acc[j].y += p * v[j].y;
            acc[j].z += p * v[j].z; acc[j].w += p * v[j].w;
        }
        z += p;
    }

#pragma unroll
    for (int j = 0; j < 4; j++)
        *(float4*)(U + rowoff + d0 + j * 256) = acc[j];
    if (lane == 0) ws[OFF_Z + gw] = z;
}

// K2: blocks [0, B*NCH*DBLK): per-chunk partial column sums of U.
//     blocks [B*NCH*DBLK, +B): inclusive prefix sum of z over s (one block per b).
__global__ void arm_k2(const float* __restrict__ U, float* __restrict__ ws) {
    int blk = blockIdx.x;
    int tid = threadIdx.x;
    if (blk >= B * NCH * DBLK) {
        int b = blk - B * NCH * DBLK;
        const float* z = ws + OFF_Z + b * S;
        float* zc = ws + OFF_ZCUM + b * S;
        float v[4];
        float loc = 0.f;
#pragma unroll
        for (int j = 0; j < 4; j++) { v[j] = z[tid * 4 + j]; loc += v[j]; }
        __shared__ float lds[256];
        lds[tid] = loc; __syncthreads();
        for (int off = 1; off < 256; off <<= 1) {
            float t = (tid >= off) ? lds[tid - off] : 0.f;
            __syncthreads();
            lds[tid] += t;
            __syncthreads();
        }
        float run = lds[tid] - loc;  // exclusive offset
#pragma unroll
        for (int j = 0; j < 4; j++) { run += v[j]; zc[tid * 4 + j] = run; }
        return;
    }
    int dblk = blk % DBLK;
    int rem = blk / DBLK;
    int ch = rem % NCH, b = rem / NCH;
    int d = dblk * 256 + tid;
    const float* Ub = U + ((size_t)b * S + ch * CH) * D + d;
    float sum = 0.f;
#pragma unroll
    for (int j = 0; j < CH; j++) sum += Ub[(size_t)j * D];
    ws[OFF_CS + (b * NCH + ch) * D + d] = sum;
}

// K3: per (b,ch,dblk): exclusive chunk-prefix from CS (redundant, L2-resident),
// then local cumsum over s within the chunk, divide by Zcum, write h in place.
__global__ void arm_k3(float* __restrict__ U, const float* __restrict__ ws) {
    int blk = blockIdx.x;
    int dblk = blk % DBLK;
    int rem = blk / DBLK;
    int ch = rem % NCH, b = rem / NCH;
    int d = dblk * 256 + threadIdx.x;

    const float* cs = ws + OFF_CS + b * NCH * D + d;
    float run = 0.f;
    for (int c2 = 0; c2 < ch; c2++) run += cs[(size_t)c2 * D];

    const float* zc = ws + OFF_ZCUM + b * S + ch * CH;
    float* Ub = U + ((size_t)b * S + ch * CH) * D + d;
#pragma unroll
    for (int j = 0; j < CH; j++) {
        run += Ub[(size_t)j * D];
        Ub[(size_t)j * D] = run / zc[j];
    }
}

extern "C" void kernel_launch(void* const* d_in, const int* in_sizes, int n_in,
                              void* d_out, int out_size, void* d_ws, size_t ws_size,
                              hipStream_t stream) {
    const float* hist  = (const float*)d_in[0];  // [12,B,S,D]
    const float* cur   = (const float*)d_in[1];  // [B,S,D]
    const float* w     = (const float*)d_in[2];  // [D]
    const float* gamma = (const float*)d_in[3];  // [D]
    const float* beta  = (const float*)d_in[4];  // [D]
    float* out = (float*)d_out;                  // [B,S,D]
    float* ws  = (float*)d_ws;

    arm_k1<<<B * S / 4, 256, 0, stream>>>(hist, cur, w, gamma, beta, out, ws);
    arm_k2<<<B * NCH * DBLK + B, 256, 0, stream>>>(out, ws);
    arm_k3<<<B * NCH * DBLK, 256, 0, stream>>>(out, ws);
}